// Round 2
// baseline (9837.000 us; speedup 1.0000x reference)
//
#include <hip/hip_runtime.h>
#include <hip/hip_bf16.h>
#include <math.h>

// StyleGAN2 StyledConvUp, B=16, Cin=Cout=512, 32x32 -> 64x64. ALL I/O fp32.
// Decomposition:
//   s[b,ic]     = style @ (mod_w/sqrt(512)).T + mod_bias          (k_style)
//   dscale[b,oc]= wscale * rsqrt(wscale^2 * sum_ic s^2*sum_k cw^2 + 1e-8)  (k_demod)
//   out[b,oc,q] = lrelu( dscale*conv3x3_parity(x*s, Keff) + nw*noise + act_b ) * sqrt(2)
// conv-transpose(stride2)+4x4 blur fuse into a dense 3x3 conv per output
// parity class (py,px)=(qy&1,qx&1), centered at r=q>>1:
//   Keff[dy,dx] = sum_{ky,kx} conv_w[ky,kx] * A[py][dy][ky] * A[px][dx][kx]
// A[p][d][k'] = kb1d[k' - p + 2d - 1], kb1d=[1,3,3,1]/4 (re-derived, verified).

__device__ const float c_A[2][9] = {
  { 0.00f, 0.25f, 0.75f,
    0.75f, 0.75f, 0.25f,
    0.25f, 0.00f, 0.00f },
  { 0.00f, 0.00f, 0.25f,
    0.25f, 0.75f, 0.75f,
    0.75f, 0.25f, 0.00f },
};

#define NB 16
#define IC 512
#define OC 512
#define H 32
#define W 32
#define WSCALE 0.014731391274719739f      /* 1/sqrt(512*9) */
#define SSCALE 0.044194173824159216f      /* 1/sqrt(512)   */

// ---- s[b,ic] = style . mod_w row, one wave per (b,ic) ----
__global__ __launch_bounds__(256) void k_style(
    const float* __restrict__ style, const float* __restrict__ mod_w,
    const float* __restrict__ mod_b, float* __restrict__ s_out) {
  int wid  = (blockIdx.x * 256 + threadIdx.x) >> 6;   // 0..8191
  int lane = threadIdx.x & 63;
  int b  = wid >> 9;
  int ic = wid & 511;
  float acc = 0.f;
  for (int j = lane; j < 512; j += 64)
    acc += style[b * 512 + j] * mod_w[ic * 512 + j];
  for (int off = 32; off > 0; off >>= 1) acc += __shfl_down(acc, off);
  if (lane == 0)
    s_out[b * 512 + ic] = acc * SSCALE + mod_b[ic];
}

// ---- dscale[b,oc] = wscale * demod, one wave per (b,oc) ----
__global__ __launch_bounds__(256) void k_demod(
    const float* __restrict__ conv_w, const float* __restrict__ s,
    float* __restrict__ dscale) {
  int wid  = (blockIdx.x * 256 + threadIdx.x) >> 6;
  int lane = threadIdx.x & 63;
  int b  = wid >> 9;
  int oc = wid & 511;
  float acc = 0.f;
  for (int ic = lane; ic < 512; ic += 64) {
    const float* wp = conv_w + (oc * 512 + ic) * 9;
    float w2 = 0.f;
    #pragma unroll
    for (int k = 0; k < 9; k++) { float w = wp[k]; w2 += w * w; }
    float sv = s[b * 512 + ic];
    acc += sv * sv * w2;
  }
  for (int off = 32; off > 0; off >>= 1) acc += __shfl_down(acc, off);
  if (lane == 0)
    dscale[b * 512 + oc] = WSCALE * rsqrtf(WSCALE * WSCALE * acc + 1e-8f);
}

// ---- fused parity conv + noise + bias + leaky relu ----
#define OCB 32
#define ICB 16
#define TR  8

__global__ __launch_bounds__(256) void k_conv(
    const float* __restrict__ x, const float* __restrict__ noise,
    const float* __restrict__ conv_w, const float* __restrict__ noise_w,
    const float* __restrict__ act_b, const float* __restrict__ s,
    const float* __restrict__ dscale, float* __restrict__ out) {
  const int bx = blockIdx.x;                 // [0,16): py,px,row-tile
  const int py = bx & 1, px = (bx >> 1) & 1;
  const int r0 = (bx >> 2) * TR;
  const int oc0 = blockIdx.y * OCB;
  const int b   = blockIdx.z;

  __shared__ float xs[ICB][TR + 2][34];
  __shared__ float kf[OCB][ICB][9];

  const int tid = threadIdx.x;
  const int pr = tid >> 5, pc = tid & 31;    // pixel (row,col) in r-space tile

  float acc[OCB];
  #pragma unroll
  for (int i = 0; i < OCB; i++) acc[i] = 0.f;

  const float* Ay = c_A[py];
  const float* Ax = c_A[px];

  for (int ic0 = 0; ic0 < IC; ic0 += ICB) {
    __syncthreads();
    // stage x*s tile with 1-px halo, zero padded
    for (int idx = tid; idx < ICB * (TR + 2) * 34; idx += 256) {
      int ic  = idx / ((TR + 2) * 34);
      int rem = idx - ic * ((TR + 2) * 34);
      int row = rem / 34;
      int col = rem - row * 34;
      int gr = r0 + row - 1;
      int gc = col - 1;
      float v = 0.f;
      if ((unsigned)gr < (unsigned)H && (unsigned)gc < (unsigned)W)
        v = x[((b * IC + ic0 + ic) * H + gr) * W + gc] * s[b * IC + ic0 + ic];
      xs[ic][row][col] = v;
    }
    // stage conv_w tile, parity-transform to Keff
    for (int p = tid; p < OCB * ICB; p += 256) {
      int oc = p >> 4, ic = p & (ICB - 1);
      const float* wp = conv_w + ((oc0 + oc) * IC + ic0 + ic) * 9;
      float w[9];
      #pragma unroll
      for (int k = 0; k < 9; k++) w[k] = wp[k];
      float t[9];
      #pragma unroll
      for (int dy = 0; dy < 3; dy++)
        #pragma unroll
        for (int kx = 0; kx < 3; kx++)
          t[dy * 3 + kx] = Ay[dy * 3 + 0] * w[0 + kx] +
                           Ay[dy * 3 + 1] * w[3 + kx] +
                           Ay[dy * 3 + 2] * w[6 + kx];
      #pragma unroll
      for (int dy = 0; dy < 3; dy++)
        #pragma unroll
        for (int dx = 0; dx < 3; dx++)
          kf[oc][ic][dy * 3 + dx] = t[dy * 3 + 0] * Ax[dx * 3 + 0] +
                                    t[dy * 3 + 1] * Ax[dx * 3 + 1] +
                                    t[dy * 3 + 2] * Ax[dx * 3 + 2];
    }
    __syncthreads();
    // accumulate: 3x3 conv, 32 oc per thread-pixel
    #pragma unroll 1
    for (int ic = 0; ic < ICB; ic++) {
      float xr[9];
      #pragma unroll
      for (int dy = 0; dy < 3; dy++)
        #pragma unroll
        for (int dx = 0; dx < 3; dx++)
          xr[dy * 3 + dx] = xs[ic][pr + dy][pc + dx];
      #pragma unroll
      for (int oc = 0; oc < OCB; oc++) {
        float a = acc[oc];
        #pragma unroll
        for (int k = 0; k < 9; k++) a += xr[k] * kf[oc][ic][k];
        acc[oc] = a;
      }
    }
  }

  // epilogue: demod scale, noise, bias, fused leaky relu
  const int qy = 2 * (r0 + pr) + py;
  const int qx = 2 * pc + px;
  const float nval = noise_w[0] * noise[b * 4096 + qy * 64 + qx];
  #pragma unroll 4
  for (int oc = 0; oc < OCB; oc++) {
    float v = acc[oc] * dscale[b * OC + oc0 + oc] + nval + act_b[oc0 + oc];
    v = (v > 0.f ? v : 0.2f * v) * 1.4142135623730951f;
    out[((b * OC + oc0 + oc) * 64 + qy) * 64 + qx] = v;
  }
}

extern "C" void kernel_launch(void* const* d_in, const int* in_sizes, int n_in,
                              void* d_out, int out_size, void* d_ws, size_t ws_size,
                              hipStream_t stream) {
  const float* x       = (const float*)d_in[0];
  const float* style   = (const float*)d_in[1];
  const float* noise   = (const float*)d_in[2];
  const float* conv_w  = (const float*)d_in[3];
  const float* mod_w   = (const float*)d_in[4];
  const float* mod_b   = (const float*)d_in[5];
  const float* noise_w = (const float*)d_in[6];
  const float* act_b   = (const float*)d_in[7];
  float* out = (float*)d_out;

  float* s_ws  = (float*)d_ws;        // 8192 floats
  float* d_sc  = s_ws + 8192;         // 8192 floats  (64 KB total)

  k_style<<<2048, 256, 0, stream>>>(style, mod_w, mod_b, s_ws);
  k_demod<<<2048, 256, 0, stream>>>(conv_w, s_ws, d_sc);
  dim3 g(16, OC / OCB, NB);
  k_conv<<<g, 256, 0, stream>>>(x, noise, conv_w, noise_w, act_b, s_ws, d_sc, out);
}

// Round 3
// 867.017 us; speedup vs baseline: 11.3458x; 11.3458x over previous
//
#include <hip/hip_runtime.h>
#include <math.h>

// StyleGAN2 StyledConvUp, B=16, Cin=Cout=512, 32x32 -> 64x64. fp32 I/O.
// Round 3: MFMA implicit-GEMM. Per (b,parity): C[oc,px] = Keff[p] @ im2col(x*s),
// M=512, N=1024, K=512ic*9taps. Keff/xs precomputed to ws as bf16; fp32 accum.
// Keff[dy,dx] = sum conv_w[ky,kx]*A[py][dy][ky]*A[px][dx][kx]  (validated R2).

typedef __attribute__((ext_vector_type(8))) __bf16 bf16x8;
typedef __attribute__((ext_vector_type(4))) float f32x4;

__device__ const float c_A[2][9] = {
  { 0.00f, 0.25f, 0.75f,
    0.75f, 0.75f, 0.25f,
    0.25f, 0.00f, 0.00f },
  { 0.00f, 0.00f, 0.25f,
    0.25f, 0.75f, 0.75f,
    0.75f, 0.25f, 0.00f },
};

#define WSCALE 0.014731391274719739f      /* 1/sqrt(512*9) */
#define SSCALE 0.044194173824159216f      /* 1/sqrt(512)   */

__device__ __forceinline__ unsigned short f2bf(float f) {
  unsigned u = __builtin_bit_cast(unsigned, f);
  u += 0x7fff + ((u >> 16) & 1);             // RTNE (inputs are finite)
  return (unsigned short)(u >> 16);
}

// ---- s[b,ic] = style . mod_w row * SSCALE + mod_b ----
__global__ __launch_bounds__(256) void k_style(
    const float* __restrict__ style, const float* __restrict__ mod_w,
    const float* __restrict__ mod_b, float* __restrict__ s_out) {
  int wid  = (blockIdx.x * 256 + threadIdx.x) >> 6;
  int lane = threadIdx.x & 63;
  int b  = wid >> 9;
  int ic = wid & 511;
  float acc = 0.f;
  for (int j = lane; j < 512; j += 64)
    acc += style[b * 512 + j] * mod_w[ic * 512 + j];
  for (int off = 32; off > 0; off >>= 1) acc += __shfl_down(acc, off);
  if (lane == 0) s_out[b * 512 + ic] = acc * SSCALE + mod_b[ic];
}

// ---- dscale[b,oc] ----
__global__ __launch_bounds__(256) void k_demod(
    const float* __restrict__ conv_w, const float* __restrict__ s,
    float* __restrict__ dscale) {
  int wid  = (blockIdx.x * 256 + threadIdx.x) >> 6;
  int lane = threadIdx.x & 63;
  int b  = wid >> 9;
  int oc = wid & 511;
  float acc = 0.f;
  for (int ic = lane; ic < 512; ic += 64) {
    const float* wp = conv_w + (oc * 512 + ic) * 9;
    float w2 = 0.f;
    #pragma unroll
    for (int k = 0; k < 9; k++) { float w = wp[k]; w2 += w * w; }
    float sv = s[b * 512 + ic];
    acc += sv * sv * w2;
  }
  for (int off = 32; off > 0; off >>= 1) acc += __shfl_down(acc, off);
  if (lane == 0)
    dscale[b * 512 + oc] = WSCALE * rsqrtf(WSCALE * WSCALE * acc + 1e-8f);
}

// ---- xs_pad[b][ic][34][34] = x*s, zero halo, bf16 ----
__global__ __launch_bounds__(256) void k_xs(
    const float* __restrict__ x, const float* __restrict__ s,
    unsigned short* __restrict__ xs_pad) {
  int idx = blockIdx.x * 256 + threadIdx.x;
  if (idx >= 16 * 512 * 34 * 34) return;
  int c = idx % 34; int t = idx / 34;
  int r = t % 34;  t /= 34;
  int ic = t & 511; int b = t >> 9;
  float v = 0.f;
  if (r >= 1 && r <= 32 && c >= 1 && c <= 32)
    v = x[((b * 512 + ic) * 32 + (r - 1)) * 32 + (c - 1)] * s[b * 512 + ic];
  xs_pad[idx] = f2bf(v);
}

// ---- Keff[p][t][oc][ic], bf16 ----
__global__ __launch_bounds__(256) void k_keff(
    const float* __restrict__ conv_w, unsigned short* __restrict__ keff) {
  int idx = blockIdx.x * 256 + threadIdx.x;   // 4*512*512
  int ic = idx & 511; int oc = (idx >> 9) & 511; int p = idx >> 18;
  const float* Ay = c_A[p & 1];
  const float* Ax = c_A[(p >> 1) & 1];
  const float* wp = conv_w + (oc * 512 + ic) * 9;
  float w[9];
  #pragma unroll
  for (int k = 0; k < 9; k++) w[k] = wp[k];
  float t9[9];
  #pragma unroll
  for (int dy = 0; dy < 3; dy++)
    #pragma unroll
    for (int kx = 0; kx < 3; kx++)
      t9[dy * 3 + kx] = Ay[dy * 3 + 0] * w[0 + kx] +
                        Ay[dy * 3 + 1] * w[3 + kx] +
                        Ay[dy * 3 + 2] * w[6 + kx];
  #pragma unroll
  for (int dy = 0; dy < 3; dy++)
    #pragma unroll
    for (int dx = 0; dx < 3; dx++) {
      float v = t9[dy * 3 + 0] * Ax[dx * 3 + 0] +
                t9[dy * 3 + 1] * Ax[dx * 3 + 1] +
                t9[dy * 3 + 2] * Ax[dx * 3 + 2];
      keff[(((p * 9 + dy * 3 + dx) * 512 + oc) << 9) + ic] = f2bf(v);
    }
}

// ---- main MFMA kernel: block = 64 oc x 256 px (16ry x 16rx), one (b,p) ----
__global__ __launch_bounds__(256, 2) void k_mm(
    const unsigned short* __restrict__ xs_pad,
    const unsigned short* __restrict__ keff,
    const float* __restrict__ noise, const float* __restrict__ noise_w,
    const float* __restrict__ act_b, const float* __restrict__ dscale,
    float* __restrict__ out) {
  // A tile: [tap][icq(quad)][ocL pad 65][8ic] -> conflict-free b128 frag reads
  __shared__ __align__(16) short A_lds[9][4][65][8];       // 37440 B
  // xs tile transposed: [pixel row hy*18+hx][ic pad 40]    // 25920 B
  __shared__ __align__(16) short xsT[18 * 18][40];

  const int pxt = blockIdx.x;                 // 0..3
  const int oc0 = blockIdx.y << 6;            // 8 tiles of 64
  const int z   = blockIdx.z;                 // p*16 + b
  const int b = z & 15, p = z >> 4;
  const int ry0 = (pxt >> 1) * 16, rx0 = (pxt & 1) * 16;

  const int tid  = threadIdx.x;
  const int lane = tid & 63, wv = tid >> 6;
  const int l15  = lane & 15, quad = lane >> 4;

  f32x4 acc[4][4];
  #pragma unroll
  for (int m = 0; m < 4; m++)
    #pragma unroll
    for (int n = 0; n < 4; n++) acc[m][n] = (f32x4)0.f;

  const unsigned short* xs_b = xs_pad + b * (512 * 34 * 34);
  const unsigned short* kf_p = keff + p * (9 * 512 * 512);

  for (int ic0 = 0; ic0 < 512; ic0 += 32) {
    __syncthreads();
    // stage xs window: 32 ic x 18x18 px (u32 = 2 bf16 along hx)
    for (int i = tid; i < 5184; i += 256) {
      int icL = i / 162;
      int rem = i - icL * 162;
      int hy = rem / 9, hp = rem - (rem / 9) * 9;
      unsigned v = *(const unsigned*)(xs_b + (ic0 + icL) * 1156 +
                                      (ry0 + hy) * 34 + rx0 + 2 * hp);
      int row = hy * 18 + 2 * hp;
      xsT[row][icL]     = (short)(v & 0xffffu);
      xsT[row + 1][icL] = (short)(v >> 16);
    }
    // stage Keff tile: 9 taps x 64 oc x 32 ic (b128, coalesced)
    for (int i = tid; i < 2304; i += 256) {
      int t = i >> 8, ocL = (i >> 2) & 63, icq = i & 3;
      bf16x8 v = *(const bf16x8*)(kf_p + ((t * 512) + oc0 + ocL) * 512 +
                                  ic0 + icq * 8);
      *(bf16x8*)&A_lds[t][icq][ocL][0] = v;
    }
    __syncthreads();
    #pragma unroll
    for (int t = 0; t < 9; t++) {
      const int dy = t / 3, dx = t - 3 * (t / 3);
      bf16x8 af[4], bf[4];
      #pragma unroll
      for (int m = 0; m < 4; m++)
        af[m] = *(const bf16x8*)&A_lds[t][quad][m * 16 + l15][0];
      #pragma unroll
      for (int n = 0; n < 4; n++) {
        int ry = (wv << 2) + n;
        bf[n] = *(const bf16x8*)&xsT[(ry + dy) * 18 + l15 + dx][quad * 8];
      }
      #pragma unroll
      for (int m = 0; m < 4; m++)
        #pragma unroll
        for (int n = 0; n < 4; n++)
          acc[m][n] = __builtin_amdgcn_mfma_f32_16x16x32_bf16(
              af[m], bf[n], acc[m][n], 0, 0, 0);
    }
  }

  // epilogue: demod, noise, bias, fused leaky-relu, fp32 store
  const float nw = noise_w[0];
  const int py = p & 1, px = (p >> 1) & 1;
  const int qx = 2 * (rx0 + l15) + px;
  #pragma unroll
  for (int n = 0; n < 4; n++) {
    int qy = 2 * (ry0 + (wv << 2) + n) + py;
    float nval = nw * noise[b * 4096 + qy * 64 + qx];
    #pragma unroll
    for (int m = 0; m < 4; m++) {
      #pragma unroll
      for (int r = 0; r < 4; r++) {
        int oc = oc0 + m * 16 + quad * 4 + r;
        float v = acc[m][n][r] * dscale[b * 512 + oc] + nval + act_b[oc];
        v = (v > 0.f ? v : 0.2f * v) * 1.4142135623730951f;
        out[((b * 512 + oc) * 64 + qy) * 64 + qx] = v;
      }
    }
  }
}

extern "C" void kernel_launch(void* const* d_in, const int* in_sizes, int n_in,
                              void* d_out, int out_size, void* d_ws, size_t ws_size,
                              hipStream_t stream) {
  const float* x       = (const float*)d_in[0];
  const float* style   = (const float*)d_in[1];
  const float* noise   = (const float*)d_in[2];
  const float* conv_w  = (const float*)d_in[3];
  const float* mod_w   = (const float*)d_in[4];
  const float* mod_b   = (const float*)d_in[5];
  const float* noise_w = (const float*)d_in[6];
  const float* act_b   = (const float*)d_in[7];
  float* out = (float*)d_out;

  char* ws = (char*)d_ws;
  float*          s_ws   = (float*)(ws);                    // 32 KB
  float*          d_sc   = (float*)(ws + 32768);            // 32 KB
  unsigned short* xs_pad = (unsigned short*)(ws + 65536);   // 18,939,904 B
  unsigned short* kf     = (unsigned short*)(ws + 19005440); // 18,874,368 B
  // total ws use: ~37.9 MB

  k_style<<<2048, 256, 0, stream>>>(style, mod_w, mod_b, s_ws);
  k_demod<<<2048, 256, 0, stream>>>(conv_w, s_ws, d_sc);
  k_xs<<<(16 * 512 * 34 * 34 + 255) / 256, 256, 0, stream>>>(x, s_ws, xs_pad);
  k_keff<<<4096, 256, 0, stream>>>(conv_w, kf);
  dim3 g(4, 8, 64);
  k_mm<<<g, 256, 0, stream>>>(xs_pad, kf, noise, noise_w, act_b, d_sc, out);
}

// Round 4
// 477.237 us; speedup vs baseline: 20.6124x; 1.8167x over previous
//
#include <hip/hip_runtime.h>
#include <math.h>

// StyleGAN2 StyledConvUp, B=16, Cin=Cout=512, 32x32 -> 64x64. fp32 I/O.
// Round 4: un-fused factorization (4x fewer FLOPs than round-3 Keff form):
//  GEMM1 (k_mm2): conv-transpose per output-parity plane, parity-sparse taps:
//    p=(py,px), taps (ky,kx) with ky=={0,2} if py==0 else {1} (same for kx),
//    pixel offset oy=(ky==2?-1:0), ox=(kx==2?-1:0)    [1D: out0[u]=w2*x[u-1]+w0*x[u]; out1[u]=w1*x[u]]
//    I[b][p][oc][uy][ux] = dscale[b][oc] * sum_taps sum_ic conv_w[oc][ic][ky][kx]*xs[b][ic][uy+oy][ux+ox]
//  k_blur: separable [1,3,3,1]/4 blur across parity planes + noise + bias + lrelu.
//  (cross-checked: composite == round-2/3-validated Keff tables)

typedef __attribute__((ext_vector_type(8))) __bf16 bf16x8;
typedef __attribute__((ext_vector_type(4))) float f32x4;

#define WSCALE 0.014731391274719739f      /* 1/sqrt(512*9) */
#define SSCALE 0.044194173824159216f      /* 1/sqrt(512)   */

__device__ __forceinline__ unsigned short f2bf(float f) {
  unsigned u = __builtin_bit_cast(unsigned, f);
  u += 0x7fff + ((u >> 16) & 1);             // RTNE, finite inputs
  return (unsigned short)(u >> 16);
}
__device__ __forceinline__ float bf2f(unsigned short h) {
  unsigned u = ((unsigned)h) << 16;
  return __builtin_bit_cast(float, u);
}

// ---- s[b,ic] ----
__global__ __launch_bounds__(256) void k_style(
    const float* __restrict__ style, const float* __restrict__ mod_w,
    const float* __restrict__ mod_b, float* __restrict__ s_out) {
  int wid  = (blockIdx.x * 256 + threadIdx.x) >> 6;
  int lane = threadIdx.x & 63;
  int b = wid >> 9, ic = wid & 511;
  float acc = 0.f;
  for (int j = lane; j < 512; j += 64)
    acc += style[b * 512 + j] * mod_w[ic * 512 + j];
  for (int off = 32; off > 0; off >>= 1) acc += __shfl_down(acc, off);
  if (lane == 0) s_out[b * 512 + ic] = acc * SSCALE + mod_b[ic];
}

// ---- dscale[b,oc] ----
__global__ __launch_bounds__(256) void k_demod(
    const float* __restrict__ conv_w, const float* __restrict__ s,
    float* __restrict__ dscale) {
  int wid  = (blockIdx.x * 256 + threadIdx.x) >> 6;
  int lane = threadIdx.x & 63;
  int b = wid >> 9, oc = wid & 511;
  float acc = 0.f;
  for (int ic = lane; ic < 512; ic += 64) {
    const float* wp = conv_w + (oc * 512 + ic) * 9;
    float w2 = 0.f;
    #pragma unroll
    for (int k = 0; k < 9; k++) { float w = wp[k]; w2 += w * w; }
    float sv = s[b * 512 + ic];
    acc += sv * sv * w2;
  }
  for (int off = 32; off > 0; off >>= 1) acc += __shfl_down(acc, off);
  if (lane == 0)
    dscale[b * 512 + oc] = WSCALE * rsqrtf(WSCALE * WSCALE * acc + 1e-8f);
}

// ---- S2[b][R=ry*34+rx][ic] = x*s pixel-major bf16; interior ry,rx in 1..32 maps
//      to x row ry-1, col rx-1; border rows zeroed by k_zero. ----
__global__ __launch_bounds__(256) void k_xs2(
    const float* __restrict__ x, const float* __restrict__ s,
    unsigned short* __restrict__ S2) {
  __shared__ float xt[64][65];
  const int b = blockIdx.z, ic0 = blockIdx.y * 64, r0 = blockIdx.x * 2;
  for (int i = threadIdx.x; i < 4096; i += 256) {
    int icL = i >> 6, pxL = i & 63;
    int gr = r0 + (pxL >> 5), gc = pxL & 31;
    xt[icL][pxL] = x[((b * 512 + ic0 + icL) * 32 + gr) * 32 + gc] * s[b * 512 + ic0 + icL];
  }
  __syncthreads();
  for (int i = threadIdx.x; i < 512; i += 256) {
    int pxL = i >> 3, icO = i & 7;
    unsigned short tmp[8];
    #pragma unroll
    for (int k = 0; k < 8; k++) tmp[k] = f2bf(xt[icO * 8 + k][pxL]);
    int gr = r0 + (pxL >> 5), gc = pxL & 31;
    int R = (gr + 1) * 34 + (gc + 1);
    *(uint4*)(&S2[((size_t)b * 1156 + R) * 512 + ic0 + icO * 8]) = *(const uint4*)tmp;
  }
}

// ---- zero the 132 border rows of each S2[b] plane ----
__global__ void k_zero(unsigned short* __restrict__ S2) {
  int b = blockIdx.y, id = blockIdx.x;
  int ry, rx;
  if (id < 34)       { ry = 0;        rx = id; }
  else if (id < 68)  { ry = 33;       rx = id - 34; }
  else if (id < 100) { ry = id - 67;  rx = 0; }
  else               { ry = id - 99;  rx = 33; }
  ((unsigned*)(S2 + ((size_t)b * 1156 + ry * 34 + rx) * 512))[threadIdx.x] = 0;
}

// ---- wt2[t][icg][oc][j] bf16 (tap-major, 8-ic groups, oc coalesced) ----
__global__ __launch_bounds__(256) void k_wt(
    const float* __restrict__ conv_w, unsigned short* __restrict__ wt2) {
  int idx = blockIdx.x * 256 + threadIdx.x;
  if (idx >= 9 * 64 * 512 * 8) return;
  int j = idx & 7, oc = (idx >> 3) & 511, icg = (idx >> 12) & 63, t = idx >> 18;
  wt2[idx] = f2bf(conv_w[(oc * 512 + icg * 8 + j) * 9 + t]);
}

// parity p = py*2+px; tap tables (tap-id ky*3+kx, Bs-local offset oy*34+ox)
__device__ const int TAPN[4]     = {4, 2, 2, 1};
__device__ const int TIDt[4][4]  = {{0,2,6,8},{1,7,0,0},{3,5,0,0},{4,0,0,0}};
__device__ const int TOFFt[4][4] = {{0,-1,-34,-35},{0,-34,0,0},{0,-1,0,0},{0,0,0,0}};

// ---- GEMM1: block 128 oc x 256 n-px (flat 34-stride grid), 4 waves 64x128 ----
__global__ __launch_bounds__(256, 2) void k_mm2(
    const unsigned short* __restrict__ S2, const unsigned short* __restrict__ wt2,
    const float* __restrict__ dscale, unsigned short* __restrict__ I, int b_base) {
  __shared__ __align__(16) unsigned short A_lds[4][4][128][8];  // 32768 B
  __shared__ __align__(16) unsigned short Bs[292][40];          // 23360 B

  const int mt = blockIdx.x, nt = blockIdx.y, z = blockIdx.z;
  const int p = z & 3, bl = z >> 2, b = b_base + bl;
  const int oc0 = mt * 128, n0 = nt * 256;
  const int tid = threadIdx.x, lane = tid & 63;
  const int wv = tid >> 6, wm = wv >> 1, wn = wv & 1;
  const int l15 = lane & 15, quad = lane >> 4;
  const int ntap = TAPN[p];

  f32x4 acc[4][8];
  #pragma unroll
  for (int m = 0; m < 4; m++)
    #pragma unroll
    for (int n = 0; n < 8; n++) acc[m][n] = (f32x4)0.f;

  const unsigned short* S2b = S2 + (size_t)b * 1156 * 512;

  for (int ic0 = 0; ic0 < 512; ic0 += 32) {
    __syncthreads();
    // stage B: 292 px-rows x 32 ic, b128 both sides, bounds-clamped
    for (int i = tid; i < 1168; i += 256) {
      int pxp = i >> 2, icq = i & 3;
      int gpx = n0 - 36 + pxp;
      uint4 v = make_uint4(0u, 0u, 0u, 0u);
      if ((unsigned)gpx < 1156u)
        v = *(const uint4*)(S2b + (size_t)gpx * 512 + ic0 + icq * 8);
      *(uint4*)(&Bs[pxp][icq * 8]) = v;
    }
    // stage A: ntap taps x 128 oc x 32 ic (coalesced from wt2)
    for (int i = tid; i < ntap * 512; i += 256) {
      int t = i >> 9, r = i & 511;
      int ocL = r & 127, icq = r >> 7;
      int tg = TIDt[p][t];
      uint4 v = *(const uint4*)(wt2 + (((size_t)(tg * 64) + (ic0 >> 3) + icq) * 512 + oc0 + ocL) * 8);
      *(uint4*)(&A_lds[t][icq][ocL][0]) = v;
    }
    __syncthreads();
    for (int t = 0; t < ntap; t++) {
      const int off = TOFFt[p][t];
      bf16x8 af[4], bfr[8];
      #pragma unroll
      for (int m = 0; m < 4; m++)
        af[m] = *(const bf16x8*)(&A_lds[t][quad][wm * 64 + m * 16 + l15][0]);
      #pragma unroll
      for (int n = 0; n < 8; n++)
        bfr[n] = *(const bf16x8*)(&Bs[36 + wn * 128 + n * 16 + l15 + off][quad * 8]);
      #pragma unroll
      for (int m = 0; m < 4; m++)
        #pragma unroll
        for (int n = 0; n < 8; n++)
          acc[m][n] = __builtin_amdgcn_mfma_f32_16x16x32_bf16(af[m], bfr[n], acc[m][n], 0, 0, 0);
    }
  }

  // epilogue: demod scale -> bf16 plane I[bl][p][oc][33*33] (row pad to 1096)
  float dsv[4][4];
  #pragma unroll
  for (int m = 0; m < 4; m++)
    #pragma unroll
    for (int r = 0; r < 4; r++)
      dsv[m][r] = dscale[b * 512 + oc0 + wm * 64 + m * 16 + quad * 4 + r];
  const size_t Ibase = ((size_t)(bl * 4 + p) * 512) * 1096;
  #pragma unroll
  for (int n = 0; n < 8; n++) {
    int nf = n0 + wn * 128 + n * 16 + l15;
    int ry = nf / 34, rx = nf - ry * 34;
    if (ry >= 1 && ry <= 33 && rx >= 1) {
      int ul = (ry - 1) * 33 + (rx - 1);
      #pragma unroll
      for (int m = 0; m < 4; m++) {
        int oc = oc0 + wm * 64 + m * 16 + quad * 4;
        #pragma unroll
        for (int r = 0; r < 4; r++)
          I[Ibase + (size_t)(oc + r) * 1096 + ul] = f2bf(acc[m][n][r] * dsv[m][r]);
      }
    }
  }
}

// ---- blur + noise + bias + lrelu: one block per (oc, b) ----
__global__ __launch_bounds__(256) void k_blur(
    const unsigned short* __restrict__ I, const float* __restrict__ noise,
    const float* __restrict__ noise_w, const float* __restrict__ act_b,
    float* __restrict__ out, int b_base) {
  __shared__ __align__(16) unsigned short Ism[4][1096];
  __shared__ float V[64][67];
  const int oc = blockIdx.x, bl = blockIdx.y, b = b_base + bl;
  for (int i = threadIdx.x; i < 548; i += 256) {
    int p = i / 137, w = i - p * 137;
    *(uint4*)(&Ism[p][w * 8]) =
        *(const uint4*)(I + ((size_t)(bl * 4 + p) * 512 + oc) * 1096 + w * 8);
  }
  __syncthreads();
  // vertical: V[qy][px*33+ux], planes p = py*2+px
  for (int i = threadIdx.x; i < 2112; i += 256) {
    int r = i / 66, col = i - r * 66;
    int px_ = (col >= 33), ux = col - 33 * px_;
    float v0 = (r >= 1) ? bf2f(Ism[2 + px_][(r - 1) * 33 + ux]) : 0.f;
    float a_ = bf2f(Ism[px_][r * 33 + ux]);
    float b_ = bf2f(Ism[2 + px_][r * 33 + ux]);
    float c_ = bf2f(Ism[px_][(r + 1) * 33 + ux]);
    float d_ = bf2f(Ism[2 + px_][(r + 1) * 33 + ux]);
    V[2 * r][col]     = 0.25f * v0 + 0.75f * a_ + 0.75f * b_ + 0.25f * c_;
    V[2 * r + 1][col] = 0.25f * a_ + 0.75f * b_ + 0.75f * c_ + 0.25f * d_;
  }
  __syncthreads();
  const float nw = noise_w[0], ab = act_b[oc];
  for (int i = threadIdx.x; i < 2048; i += 256) {
    int qy = i >> 5, rx = i & 31;
    float w0 = (rx >= 1) ? V[qy][33 + rx - 1] : 0.f;
    float a_ = V[qy][rx];
    float b_ = V[qy][33 + rx];
    float c_ = V[qy][rx + 1];
    float d_ = V[qy][33 + rx + 1];
    float o0 = 0.25f * w0 + 0.75f * a_ + 0.75f * b_ + 0.25f * c_;
    float o1 = 0.25f * a_ + 0.75f * b_ + 0.75f * c_ + 0.25f * d_;
    const float2 nv = *(const float2*)(noise + b * 4096 + qy * 64 + 2 * rx);
    o0 += nw * nv.x + ab;  o1 += nw * nv.y + ab;
    o0 = (o0 > 0.f ? o0 : 0.2f * o0) * 1.4142135623730951f;
    o1 = (o1 > 0.f ? o1 : 0.2f * o1) * 1.4142135623730951f;
    float2 ov = make_float2(o0, o1);
    *(float2*)(out + (((size_t)b * 512 + oc) * 64 + qy) * 64 + 2 * rx) = ov;
  }
}

extern "C" void kernel_launch(void* const* d_in, const int* in_sizes, int n_in,
                              void* d_out, int out_size, void* d_ws, size_t ws_size,
                              hipStream_t stream) {
  const float* x       = (const float*)d_in[0];
  const float* style   = (const float*)d_in[1];
  const float* noise   = (const float*)d_in[2];
  const float* conv_w  = (const float*)d_in[3];
  const float* mod_w   = (const float*)d_in[4];
  const float* mod_b   = (const float*)d_in[5];
  const float* noise_w = (const float*)d_in[6];
  const float* act_b   = (const float*)d_in[7];
  float* out = (float*)d_out;

  char* ws = (char*)d_ws;
  float*          s_ws = (float*)ws;                       // 32 KB
  float*          d_sc = (float*)(ws + 32768);             // 32 KB
  unsigned short* S2   = (unsigned short*)(ws + 65536);    // 18,939,904 B
  unsigned short* wt2  = (unsigned short*)(ws + 65536 + 18939904);  // 4,718,592 B
  unsigned short* I    = (unsigned short*)(ws + 65536 + 18939904 + 4718592);
  const size_t fixed = 65536ull + 18939904ull + 4718592ull;          // 23.7 MB
  const size_t i_full = (size_t)16 * 4 * 512 * 1096 * 2;             // 71.8 MB

  int nb = 16;                                  // batch chunk sized to ws budget
  if (ws_size < fixed + i_full)     nb = 8;
  if (ws_size < fixed + i_full / 2) nb = 4;
  if (ws_size < fixed + i_full / 4) nb = 2;

  k_style<<<2048, 256, 0, stream>>>(style, mod_w, mod_b, s_ws);
  k_demod<<<2048, 256, 0, stream>>>(conv_w, s_ws, d_sc);
  k_xs2<<<dim3(16, 8, 16), 256, 0, stream>>>(x, s_ws, S2);
  k_zero<<<dim3(132, 16), 256, 0, stream>>>(S2);
  k_wt<<<9216, 256, 0, stream>>>(conv_w, wt2);
  for (int b0 = 0; b0 < 16; b0 += nb) {
    k_mm2<<<dim3(4, 5, nb * 4), 256, 0, stream>>>(S2, wt2, d_sc, I, b0);
    k_blur<<<dim3(512, nb), 256, 0, stream>>>(I, noise, noise_w, act_b, out, b0);
  }
}